// Round 1
// baseline (929.449 us; speedup 1.0000x reference)
//
#include <hip/hip_runtime.h>
#include <hip/hip_bf16.h>
#include <type_traits>

typedef unsigned short u16;
typedef __attribute__((ext_vector_type(8))) short s16x8;
typedef __attribute__((ext_vector_type(4))) float f32x4;

// fp32 -> bf16 round-to-nearest-even
__device__ __forceinline__ u16 f2bf(float f) {
    union { float f; unsigned u; } c; c.f = f;
    unsigned r = c.u + 0x7fffu + ((c.u >> 16) & 1u);
    return (u16)(r >> 16);
}

// ---------------- prep: row-sums of a (deg = rowsum + 1 from +I), optional a->bf16 ----------------
template<bool CVT>
__global__ __launch_bounds__(256) void rowsum_kernel(const float* __restrict__ a,
                                                     float* __restrict__ dsc,
                                                     u16* __restrict__ ab) {
    const int wave = threadIdx.x >> 6, lane = threadIdx.x & 63;
    const long row = (long)blockIdx.x * 4 + wave;   // 65536 rows, each 1024 floats
    const float4* a4 = (const float4*)(a + row * 1024);
    float s = 0.f;
    #pragma unroll
    for (int i = 0; i < 4; ++i) {
        float4 v = a4[i * 64 + lane];
        if (CVT) {
            union { u16 u[4]; uint2 w; } cv;
            cv.u[0] = f2bf(v.x); cv.u[1] = f2bf(v.y);
            cv.u[2] = f2bf(v.z); cv.u[3] = f2bf(v.w);
            *(uint2*)(ab + row * 1024 + (long)(i * 64 + lane) * 4) = cv.w;
        }
        s += v.x + v.y + v.z + v.w;
    }
    #pragma unroll
    for (int off = 32; off > 0; off >>= 1) s += __shfl_down(s, off, 64);
    if (lane == 0) dsc[row] = rsqrtf(s + 1.0f + 1e-8f);
}

// ---------------- prep: xst[b][n][j] = bf16(d_j * x[b][j][n])  (transpose so GEMM1 B is [N,K]) ----
__global__ __launch_bounds__(256) void xst_kernel(const float* __restrict__ x,
                                                  const float* __restrict__ dsc,
                                                  u16* __restrict__ xst) {
    __shared__ u16 ls[64][65];
    const int b  = blockIdx.z;
    const int n0 = blockIdx.x * 64;   // over IN_DIM=512
    const int j0 = blockIdx.y * 64;   // over N=1024
    const int t  = threadIdx.x;
    {
        int jj = t >> 4, nn = (t & 15) * 4;
        #pragma unroll
        for (int it = 0; it < 4; ++it, jj += 16) {
            float dj = dsc[b * 1024 + j0 + jj];
            float4 v = *(const float4*)(x + ((long)(b * 1024 + j0 + jj)) * 512 + n0 + nn);
            ls[jj][nn + 0] = f2bf(v.x * dj);
            ls[jj][nn + 1] = f2bf(v.y * dj);
            ls[jj][nn + 2] = f2bf(v.z * dj);
            ls[jj][nn + 3] = f2bf(v.w * dj);
        }
    }
    __syncthreads();
    {
        int nn = t >> 2;
        int jv = (t & 3) * 8;
        #pragma unroll
        for (int it = 0; it < 2; ++it, jv += 32) {
            union { u16 u[8]; uint4 w; } cv;
            #pragma unroll
            for (int u = 0; u < 8; ++u) cv.u[u] = ls[jv + u][nn];
            *(uint4*)(xst + ((long)b * 512 + n0 + nn) * 1024 + j0 + jv) = cv.w;
        }
    }
}

// ---------------- prep: weights -> bf16; W_mu/W_lv concatenated into [512][1024] -----------------
__global__ __launch_bounds__(256) void cvt_weights(const float* __restrict__ W1,
                                                   const float* __restrict__ Wmu,
                                                   const float* __restrict__ Wlv,
                                                   u16* __restrict__ w1b,
                                                   u16* __restrict__ wml) {
    int i = blockIdx.x * 256 + threadIdx.x;          // 524288 = 1024*512 = 512*1024
    w1b[i] = f2bf(W1[i]);
    wml[i] = f2bf(i < 262144 ? Wmu[i] : Wlv[i - 262144]);
}

// ---------------- GEMM: C[m,n] = sum_k A[m,k] * Bt[n,k]   (Bt is [N,K] bf16) --------------------
// 128x128 block tile, BK=32, 256 thr (4 waves, 2x2 of 64x64), mfma_f32_16x16x32_bf16.
// EPI 1: h = bf16(d_i*(acc + d_i*x)), out [65536][512]
// EPI 2: hid = bf16(relu(acc + b1[n])), out [65536][1024]
// EPI 3: n<256 -> mu = acc + b_mu[n]; else lv = acc + b_lv[n-256] (fp32)
template<int EPI, typename TA>
__global__ __launch_bounds__(256) void gemm_bt(
    const TA* __restrict__ A, const u16* __restrict__ Bt,
    int K, long aBStride, long bBStride,
    const float* __restrict__ dsc, const float* __restrict__ xin,
    u16* __restrict__ outb,
    const float* __restrict__ bias0, const float* __restrict__ bias1,
    float* __restrict__ outMu, float* __restrict__ outLv)
{
    __shared__ __align__(16) u16 As[128 * 40];   // rows padded to 40 u16 (bank stride 20 words)
    __shared__ __align__(16) u16 Bs[128 * 40];
    const int bz = blockIdx.z;
    const TA* Ab = A + (long)bz * aBStride;
    const u16* Bb = Bt + (long)bz * bBStride;
    const int n0 = blockIdx.x * 128, m0 = blockIdx.y * 128;
    const int t = threadIdx.x;
    const int wave = t >> 6, lane = t & 63, quad = lane >> 4, tr = lane & 15;
    const int wm = (wave >> 1) * 64, wn = (wave & 1) * 64;

    f32x4 acc[4][4];
    #pragma unroll
    for (int i = 0; i < 4; ++i)
        #pragma unroll
        for (int j = 0; j < 4; ++j) acc[i][j] = (f32x4){0.f, 0.f, 0.f, 0.f};

    const int mm = t >> 2, kk = (t & 3) * 8;     // staging: row mm(+64), 8 elems at kk
    for (int k0 = 0; k0 < K; k0 += 32) {
        #pragma unroll
        for (int it = 0; it < 2; ++it) {
            const int r = mm + it * 64;
            if constexpr (std::is_same<TA, float>::value) {
                const float4* p = (const float4*)(Ab + (long)(m0 + r) * K + k0 + kk);
                float4 v0 = p[0], v1 = p[1];
                union { u16 u[8]; uint4 w; } cv;
                cv.u[0]=f2bf(v0.x); cv.u[1]=f2bf(v0.y); cv.u[2]=f2bf(v0.z); cv.u[3]=f2bf(v0.w);
                cv.u[4]=f2bf(v1.x); cv.u[5]=f2bf(v1.y); cv.u[6]=f2bf(v1.z); cv.u[7]=f2bf(v1.w);
                *(uint4*)&As[r * 40 + kk] = cv.w;
            } else {
                uint4 v = *(const uint4*)(Ab + (long)(m0 + r) * K + k0 + kk);
                *(uint4*)&As[r * 40 + kk] = v;
            }
        }
        #pragma unroll
        for (int it = 0; it < 2; ++it) {
            const int r = mm + it * 64;
            uint4 v = *(const uint4*)(Bb + (long)(n0 + r) * K + k0 + kk);
            *(uint4*)&Bs[r * 40 + kk] = v;
        }
        __syncthreads();
        s16x8 af[4], bfv[4];
        #pragma unroll
        for (int mi = 0; mi < 4; ++mi)
            af[mi] = *(const s16x8*)&As[(wm + mi * 16 + tr) * 40 + quad * 8];
        #pragma unroll
        for (int ni = 0; ni < 4; ++ni)
            bfv[ni] = *(const s16x8*)&Bs[(wn + ni * 16 + tr) * 40 + quad * 8];
        #pragma unroll
        for (int mi = 0; mi < 4; ++mi)
            #pragma unroll
            for (int ni = 0; ni < 4; ++ni)
                acc[mi][ni] = __builtin_amdgcn_mfma_f32_16x16x32_bf16(af[mi], bfv[ni], acc[mi][ni], 0, 0, 0);
        __syncthreads();
    }

    // epilogue — C/D layout: col = lane&15, row = quad*4 + reg  (m89-verified)
    #pragma unroll
    for (int mi = 0; mi < 4; ++mi) {
        #pragma unroll
        for (int ni = 0; ni < 4; ++ni) {
            const int gn = n0 + wn + ni * 16 + tr;
            #pragma unroll
            for (int r = 0; r < 4; ++r) {
                const int gm = m0 + wm + mi * 16 + quad * 4 + r;
                float v = acc[mi][ni][r];
                if constexpr (EPI == 1) {
                    long row = (long)bz * 1024 + gm;
                    float di = dsc[row];
                    float xv = xin[row * 512 + gn];
                    outb[row * 512 + gn] = f2bf(di * (v + di * xv));
                } else if constexpr (EPI == 2) {
                    float hv = v + bias0[gn];
                    outb[(long)gm * 1024 + gn] = f2bf(hv > 0.f ? hv : 0.f);
                } else {
                    if (gn < 256) outMu[(long)gm * 256 + gn] = v + bias0[gn];
                    else          outLv[(long)gm * 256 + (gn - 256)] = v + bias1[gn - 256];
                }
            }
        }
    }
}

extern "C" void kernel_launch(void* const* d_in, const int* in_sizes, int n_in,
                              void* d_out, int out_size, void* d_ws, size_t ws_size,
                              hipStream_t stream) {
    const float* x   = (const float*)d_in[0];   // [64,1024,512]
    const float* a   = (const float*)d_in[1];   // [64,1024,1024]
    const float* W1  = (const float*)d_in[2];   // [1024,512]
    const float* b1  = (const float*)d_in[3];   // [1024]
    const float* Wmu = (const float*)d_in[4];   // [256,1024]
    const float* bmu = (const float*)d_in[5];   // [256]
    const float* Wlv = (const float*)d_in[6];   // [256,1024]
    const float* blv = (const float*)d_in[7];   // [256]
    float* out = (float*)d_out;                 // mu [64,1024,256] then logvar [64,1024,256]

    char* base = (char*)d_ws;
    size_t off = 0;
    auto take = [&](size_t bytes) { char* p = base + off; off += (bytes + 255) & ~(size_t)255; return p; };
    float* dsc = (float*)take((size_t)65536 * 4);              // D^-1/2 per (b,i)
    u16*  xst  = (u16*)take((size_t)64 * 512 * 1024 * 2);      // [b][n][j] bf16
    u16*  h    = (u16*)take((size_t)65536 * 512 * 2);          // GEMM1 out
    u16*  hid  = (u16*)take((size_t)65536 * 1024 * 2);         // GEMM2 out
    u16*  w1b  = (u16*)take((size_t)1024 * 512 * 2);
    u16*  wml  = (u16*)take((size_t)512 * 1024 * 2);
    u16*  ab   = (u16*)take((size_t)64 * 1024 * 1024 * 2);     // optional bf16 copy of a
    const bool useAb = (off <= ws_size);

    if (useAb) rowsum_kernel<true ><<<16384, 256, 0, stream>>>(a, dsc, ab);
    else       rowsum_kernel<false><<<16384, 256, 0, stream>>>(a, dsc, nullptr);
    xst_kernel<<<dim3(8, 16, 64), 256, 0, stream>>>(x, dsc, xst);
    cvt_weights<<<2048, 256, 0, stream>>>(W1, Wmu, Wlv, w1b, wml);

    if (useAb)
        gemm_bt<1, u16><<<dim3(4, 8, 64), 256, 0, stream>>>(
            ab, xst, 1024, 1024L * 1024, 512L * 1024,
            dsc, x, h, nullptr, nullptr, nullptr, nullptr);
    else
        gemm_bt<1, float><<<dim3(4, 8, 64), 256, 0, stream>>>(
            a, xst, 1024, 1024L * 1024, 512L * 1024,
            dsc, x, h, nullptr, nullptr, nullptr, nullptr);

    gemm_bt<2, u16><<<dim3(8, 512, 1), 256, 0, stream>>>(
        h, w1b, 512, 0, 0, nullptr, nullptr, hid, b1, nullptr, nullptr, nullptr);

    gemm_bt<3, u16><<<dim3(4, 512, 1), 256, 0, stream>>>(
        hid, wml, 1024, 0, 0, nullptr, nullptr, nullptr, bmu, blv,
        out, out + (size_t)65536 * 256);
}

// Round 2
// 875.857 us; speedup vs baseline: 1.0612x; 1.0612x over previous
//
#include <hip/hip_runtime.h>
#include <hip/hip_bf16.h>
#include <type_traits>

typedef unsigned short u16;
typedef __attribute__((ext_vector_type(8))) short s16x8;
typedef __attribute__((ext_vector_type(4))) float f32x4;

// fp32 -> bf16 round-to-nearest-even
__device__ __forceinline__ u16 f2bf(float f) {
    union { float f; unsigned u; } c; c.f = f;
    unsigned r = c.u + 0x7fffu + ((c.u >> 16) & 1u);
    return (u16)(r >> 16);
}

// async global->LDS, 16 bytes/lane. LDS dest is wave-uniform base + lane*16.
__device__ __forceinline__ void gld_lds16(const u16* g, u16* l) {
    __builtin_amdgcn_global_load_lds(
        (const __attribute__((address_space(1))) void*)g,
        (__attribute__((address_space(3))) void*)l, 16, 0, 0);
}

// ---------------- prep: row-sums of a; a->bf16 with +I folded into the diagonal -----------------
template<bool CVT>
__global__ __launch_bounds__(256) void rowsum_kernel(const float* __restrict__ a,
                                                     float* __restrict__ dsc,
                                                     u16* __restrict__ ab) {
    const int wave = threadIdx.x >> 6, lane = threadIdx.x & 63;
    const long row = (long)blockIdx.x * 4 + wave;   // 65536 rows, each 1024 floats
    const int diag = (int)(row & 1023);             // column index of the +I element
    const float4* a4 = (const float4*)(a + row * 1024);
    float s = 0.f;
    #pragma unroll
    for (int i = 0; i < 4; ++i) {
        float4 v = a4[i * 64 + lane];
        s += v.x + v.y + v.z + v.w;                 // raw rowsum (deg adds +1 below)
        if (CVT) {
            const int c0 = (i * 64 + lane) * 4;
            float e[4] = {v.x, v.y, v.z, v.w};
            if (diag >= c0 && diag < c0 + 4) e[diag - c0] += 1.0f;  // fold +I into bf16 A
            union { u16 u[4]; uint2 w; } cv;
            cv.u[0] = f2bf(e[0]); cv.u[1] = f2bf(e[1]);
            cv.u[2] = f2bf(e[2]); cv.u[3] = f2bf(e[3]);
            *(uint2*)(ab + row * 1024 + c0) = cv.w;
        }
    }
    #pragma unroll
    for (int off = 32; off > 0; off >>= 1) s += __shfl_down(s, off, 64);
    if (lane == 0) dsc[row] = rsqrtf(s + 1.0f + 1e-8f);
}

// ---------------- prep: xst[b][n][j] = bf16(d_j * x[b][j][n])  (transpose so GEMM1 B is [N,K]) ----
__global__ __launch_bounds__(256) void xst_kernel(const float* __restrict__ x,
                                                  const float* __restrict__ dsc,
                                                  u16* __restrict__ xst) {
    __shared__ u16 ls[64][65];
    const int b  = blockIdx.z;
    const int n0 = blockIdx.x * 64;   // over IN_DIM=512
    const int j0 = blockIdx.y * 64;   // over N=1024
    const int t  = threadIdx.x;
    {
        int jj = t >> 4, nn = (t & 15) * 4;
        #pragma unroll
        for (int it = 0; it < 4; ++it, jj += 16) {
            float dj = dsc[b * 1024 + j0 + jj];
            float4 v = *(const float4*)(x + ((long)(b * 1024 + j0 + jj)) * 512 + n0 + nn);
            ls[jj][nn + 0] = f2bf(v.x * dj);
            ls[jj][nn + 1] = f2bf(v.y * dj);
            ls[jj][nn + 2] = f2bf(v.z * dj);
            ls[jj][nn + 3] = f2bf(v.w * dj);
        }
    }
    __syncthreads();
    {
        int nn = t >> 2;
        int jv = (t & 3) * 8;
        #pragma unroll
        for (int it = 0; it < 2; ++it, jv += 32) {
            union { u16 u[8]; uint4 w; } cv;
            #pragma unroll
            for (int u = 0; u < 8; ++u) cv.u[u] = ls[jv + u][nn];
            *(uint4*)(xst + ((long)b * 512 + n0 + nn) * 1024 + j0 + jv) = cv.w;
        }
    }
}

// ---------------- prep: weights -> bf16; W_mu/W_lv concatenated into [512][1024] -----------------
__global__ __launch_bounds__(256) void cvt_weights(const float* __restrict__ W1,
                                                   const float* __restrict__ Wmu,
                                                   const float* __restrict__ Wlv,
                                                   u16* __restrict__ w1b,
                                                   u16* __restrict__ wml) {
    int i = blockIdx.x * 256 + threadIdx.x;          // 524288 = 1024*512 = 512*1024
    w1b[i] = f2bf(W1[i]);
    wml[i] = f2bf(i < 262144 ? Wmu[i] : Wlv[i - 262144]);
}

// ---------------- GEMM (m97 structure): C[m,n] = sum_k A[m,k] * Bt[n,k], both bf16 [.,K] ---------
// 128x128 block tile, BK=32, 256 thr (4 waves, 2x2 of 64x64), mfma_f32_16x16x32_bf16,
// global_load_lds width-16 staging into UNPADDED 128x32 LDS tiles.
// EPI 1: h   = bf16(d_i * acc)                 -> [65536][512]   (+I already folded into A)
// EPI 2: hid = bf16(relu(acc + b1[n]))         -> [65536][1024]
// EPI 3: n<256 -> mu = acc + b_mu[n]; else lv = acc + b_lv[n-256]  (fp32)
template<int EPI>
__global__ __launch_bounds__(256) void gemm_lds(
    const u16* __restrict__ A, const u16* __restrict__ Bt,
    int K, long aBStride, long bBStride,
    const float* __restrict__ dsc,
    u16* __restrict__ outb,
    const float* __restrict__ bias0, const float* __restrict__ bias1,
    float* __restrict__ outMu, float* __restrict__ outLv)
{
    __shared__ __align__(16) u16 As[128 * 32];   // unpadded: required by global_load_lds layout
    __shared__ __align__(16) u16 Bs[128 * 32];
    const int bz = blockIdx.z;
    const u16* Ab = A + (long)bz * aBStride;
    const u16* Bb = Bt + (long)bz * bBStride;
    const int n0 = blockIdx.x * 128, m0 = blockIdx.y * 128;
    const int t = threadIdx.x;
    const int wave = t >> 6, lane = t & 63, quad = lane >> 4, tr = lane & 15;
    const int wm = (wave >> 1) * 64, wn = (wave & 1) * 64;

    // staging: wave w covers tile rows [w*32, w*32+32) in 2 iters of 16 rows;
    // lane l -> row it*16 + l/4, 16B chunk l%4. LDS offset = wave-uniform base + lane*16.
    const int srowA = wave * 32 + (lane >> 2);
    const int scol  = (lane & 3) * 8;            // u16 units
    u16* ldsA0 = As + wave * 1024;               // wave*32 rows * 32 u16
    u16* ldsB0 = Bs + wave * 1024;

    f32x4 acc[4][4];
    #pragma unroll
    for (int i = 0; i < 4; ++i)
        #pragma unroll
        for (int j = 0; j < 4; ++j) acc[i][j] = (f32x4){0.f, 0.f, 0.f, 0.f};

    for (int k0 = 0; k0 < K; k0 += 32) {
        #pragma unroll
        for (int it = 0; it < 2; ++it) {
            gld_lds16(Ab + (long)(m0 + srowA + it * 16) * K + k0 + scol, ldsA0 + it * 512);
            gld_lds16(Bb + (long)(n0 + srowA + it * 16) * K + k0 + scol, ldsB0 + it * 512);
        }
        __syncthreads();
        s16x8 af[4], bfv[4];
        #pragma unroll
        for (int mi = 0; mi < 4; ++mi)
            af[mi] = *(const s16x8*)&As[(wm + mi * 16 + tr) * 32 + quad * 8];
        #pragma unroll
        for (int ni = 0; ni < 4; ++ni)
            bfv[ni] = *(const s16x8*)&Bs[(wn + ni * 16 + tr) * 32 + quad * 8];
        #pragma unroll
        for (int mi = 0; mi < 4; ++mi)
            #pragma unroll
            for (int ni = 0; ni < 4; ++ni)
                acc[mi][ni] = __builtin_amdgcn_mfma_f32_16x16x32_bf16(af[mi], bfv[ni], acc[mi][ni], 0, 0, 0);
        __syncthreads();
    }

    // epilogue — C/D layout: col = lane&15, row = quad*4 + reg  (m89-verified)
    #pragma unroll
    for (int mi = 0; mi < 4; ++mi) {
        #pragma unroll
        for (int ni = 0; ni < 4; ++ni) {
            const int gn = n0 + wn + ni * 16 + tr;
            #pragma unroll
            for (int r = 0; r < 4; ++r) {
                const int gm = m0 + wm + mi * 16 + quad * 4 + r;
                float v = acc[mi][ni][r];
                if constexpr (EPI == 1) {
                    long row = (long)bz * 1024 + gm;
                    outb[row * 512 + gn] = f2bf(dsc[row] * v);
                } else if constexpr (EPI == 2) {
                    float hv = v + bias0[gn];
                    outb[(long)gm * 1024 + gn] = f2bf(hv > 0.f ? hv : 0.f);
                } else {
                    if (gn < 256) outMu[(long)gm * 256 + gn] = v + bias0[gn];
                    else          outLv[(long)gm * 256 + (gn - 256)] = v + bias1[gn - 256];
                }
            }
        }
    }
}

// ---------------- fallback GEMM1 (fp32 A inline-converted) if ws can't hold bf16 a ---------------
__global__ __launch_bounds__(256) void gemm_f32a(
    const float* __restrict__ A, const u16* __restrict__ Bt,
    const float* __restrict__ dsc, const float* __restrict__ xin,
    u16* __restrict__ outb)
{
    __shared__ __align__(16) u16 As[128 * 40];
    __shared__ __align__(16) u16 Bs[128 * 40];
    const int bz = blockIdx.z;
    const float* Ab = A + (long)bz * 1024 * 1024;
    const u16* Bb = Bt + (long)bz * 512 * 1024;
    const int n0 = blockIdx.x * 128, m0 = blockIdx.y * 128;
    const int t = threadIdx.x;
    const int wave = t >> 6, lane = t & 63, quad = lane >> 4, tr = lane & 15;
    const int wm = (wave >> 1) * 64, wn = (wave & 1) * 64;
    const int K = 1024;

    f32x4 acc[4][4];
    #pragma unroll
    for (int i = 0; i < 4; ++i)
        #pragma unroll
        for (int j = 0; j < 4; ++j) acc[i][j] = (f32x4){0.f, 0.f, 0.f, 0.f};

    const int mm = t >> 2, kk = (t & 3) * 8;
    for (int k0 = 0; k0 < K; k0 += 32) {
        #pragma unroll
        for (int it = 0; it < 2; ++it) {
            const int r = mm + it * 64;
            const float4* p = (const float4*)(Ab + (long)(m0 + r) * K + k0 + kk);
            float4 v0 = p[0], v1 = p[1];
            union { u16 u[8]; uint4 w; } cv;
            cv.u[0]=f2bf(v0.x); cv.u[1]=f2bf(v0.y); cv.u[2]=f2bf(v0.z); cv.u[3]=f2bf(v0.w);
            cv.u[4]=f2bf(v1.x); cv.u[5]=f2bf(v1.y); cv.u[6]=f2bf(v1.z); cv.u[7]=f2bf(v1.w);
            *(uint4*)&As[r * 40 + kk] = cv.w;
            uint4 v = *(const uint4*)(Bb + (long)(n0 + r) * K + k0 + kk);
            *(uint4*)&Bs[r * 40 + kk] = v;
        }
        __syncthreads();
        s16x8 af[4], bfv[4];
        #pragma unroll
        for (int mi = 0; mi < 4; ++mi)
            af[mi] = *(const s16x8*)&As[(wm + mi * 16 + tr) * 40 + quad * 8];
        #pragma unroll
        for (int ni = 0; ni < 4; ++ni)
            bfv[ni] = *(const s16x8*)&Bs[(wn + ni * 16 + tr) * 40 + quad * 8];
        #pragma unroll
        for (int mi = 0; mi < 4; ++mi)
            #pragma unroll
            for (int ni = 0; ni < 4; ++ni)
                acc[mi][ni] = __builtin_amdgcn_mfma_f32_16x16x32_bf16(af[mi], bfv[ni], acc[mi][ni], 0, 0, 0);
        __syncthreads();
    }
    #pragma unroll
    for (int mi = 0; mi < 4; ++mi)
        #pragma unroll
        for (int ni = 0; ni < 4; ++ni) {
            const int gn = n0 + wn + ni * 16 + tr;
            #pragma unroll
            for (int r = 0; r < 4; ++r) {
                const int gm = m0 + wm + mi * 16 + quad * 4 + r;
                long row = (long)bz * 1024 + gm;
                float di = dsc[row];
                outb[row * 512 + gn] = f2bf(di * (acc[mi][ni][r] + di * xin[row * 512 + gn]));
            }
        }
}

extern "C" void kernel_launch(void* const* d_in, const int* in_sizes, int n_in,
                              void* d_out, int out_size, void* d_ws, size_t ws_size,
                              hipStream_t stream) {
    const float* x   = (const float*)d_in[0];   // [64,1024,512]
    const float* a   = (const float*)d_in[1];   // [64,1024,1024]
    const float* W1  = (const float*)d_in[2];   // [1024,512]
    const float* b1  = (const float*)d_in[3];   // [1024]
    const float* Wmu = (const float*)d_in[4];   // [256,1024]
    const float* bmu = (const float*)d_in[5];   // [256]
    const float* Wlv = (const float*)d_in[6];   // [256,1024]
    const float* blv = (const float*)d_in[7];   // [256]
    float* out = (float*)d_out;                 // mu [64,1024,256] then logvar [64,1024,256]

    char* base = (char*)d_ws;
    size_t off = 0;
    auto take = [&](size_t bytes) { char* p = base + off; off += (bytes + 255) & ~(size_t)255; return p; };
    float* dsc = (float*)take((size_t)65536 * 4);              // D^-1/2 per (b,i)
    u16*  xst  = (u16*)take((size_t)64 * 512 * 1024 * 2);      // [b][n][j] bf16
    u16*  h    = (u16*)take((size_t)65536 * 512 * 2);          // GEMM1 out
    u16*  hid  = (u16*)take((size_t)65536 * 1024 * 2);         // GEMM2 out
    u16*  w1b  = (u16*)take((size_t)1024 * 512 * 2);
    u16*  wml  = (u16*)take((size_t)512 * 1024 * 2);
    u16*  ab   = (u16*)take((size_t)64 * 1024 * 1024 * 2);     // bf16 copy of (a + I)
    const bool useAb = (off <= ws_size);

    if (useAb) rowsum_kernel<true ><<<16384, 256, 0, stream>>>(a, dsc, ab);
    else       rowsum_kernel<false><<<16384, 256, 0, stream>>>(a, dsc, nullptr);
    xst_kernel<<<dim3(8, 16, 64), 256, 0, stream>>>(x, dsc, xst);
    cvt_weights<<<2048, 256, 0, stream>>>(W1, Wmu, Wlv, w1b, wml);

    if (useAb)
        gemm_lds<1><<<dim3(4, 8, 64), 256, 0, stream>>>(
            ab, xst, 1024, 1024L * 1024, 512L * 1024,
            dsc, h, nullptr, nullptr, nullptr, nullptr);
    else
        gemm_f32a<<<dim3(4, 8, 64), 256, 0, stream>>>(a, xst, dsc, x, h);

    gemm_lds<2><<<dim3(8, 512, 1), 256, 0, stream>>>(
        h, w1b, 512, 0, 0, nullptr, hid, b1, nullptr, nullptr, nullptr);

    gemm_lds<3><<<dim3(4, 512, 1), 256, 0, stream>>>(
        hid, wml, 1024, 0, 0, nullptr, nullptr, bmu, blv,
        out, out + (size_t)65536 * 256);
}